// Round 2
// baseline (1797.994 us; speedup 1.0000x reference)
//
#include <hip/hip_runtime.h>

// WindowAttention fused kernel for MI355X (gfx950).
// R2 (resubmit after infra failure): 512 threads = 8 waves per block (was
// 256/4). LDS (163328 B) still caps at 1 block/CU, but 8 waves -> 2
// waves/SIMD: per-wave serial work halves and LDS/global latencies are hidden
// by intra-SIMD interleave. Each wave owns a 16-row band (row0 = wv*16); all
// phase/barrier/buffer structure unchanged from the verified 256-thread
// version. Mask values are head-invariant -> loaded into 32 regs once per
// block (was re-read from global every head in pass A).
//
// Strategy: one workgroup per window block b (grid=2048). Fully fused:
// qkv GEMM -> per-head scores (qk MFMA + rpe via 225-table GEMM+gather) ->
// softmax -> p@v MFMA + p@v_rpe via scatter+GEMM -> proj GEMM.
// All matmuls in bf16 MFMA 16x16x32, fp32 accumulate.
//
// rpe_table head packing is [H,96]->split(3) (q_rpe=h*96+0..31,
// k_rpe=h*96+32.., v_rpe=h*96+64..), NOT the qkv [3,H,32] packing. Permute in
// wa_prep so the main kernel's [3,H,32] view stays unchanged.

#define SCALE 0.17677669529663687f   // 32^-0.5

typedef __attribute__((ext_vector_type(8))) __bf16 bf16x8;
typedef __attribute__((ext_vector_type(4))) float  f32x4;

__device__ __forceinline__ float bf2f(ushort u){
  union { unsigned int i; float f; } v; v.i = ((unsigned int)u) << 16; return v.f;
}
__device__ __forceinline__ ushort f2bf(float f){
  union { float f; unsigned int i; } v; v.f = f;
  unsigned int r = v.i + 0x7FFFu + ((v.i >> 16) & 1u);   // RNE
  return (ushort)(r >> 16);
}
__device__ __forceinline__ bf16x8 ld16(const ushort* p){          // 16B-aligned
  int4 v = *(const int4*)p;
  return __builtin_bit_cast(bf16x8, v);
}
__device__ __forceinline__ bf16x8 ld8(const ushort* p){           // 8B-aligned
  int2 lo = *(const int2*)p;
  int2 hi = *(const int2*)(p + 4);
  int4 v = make_int4(lo.x, lo.y, hi.x, hi.y);
  return __builtin_bit_cast(bf16x8, v);
}
__device__ __forceinline__ f32x4 mfma16(bf16x8 a, bf16x8 b, f32x4 c){
  return __builtin_amdgcn_mfma_f32_16x16x32_bf16(a, b, c, 0, 0, 0);
}
// REL_IDX computed on the fly: ip,jp in [0,64) positions of the 8x8 window
__device__ __forceinline__ int relidx(int ip, int jp){
  return ((ip >> 3) - (jp >> 3) + 7) * 15 + ((ip & 7) - (jp & 7) + 7);
}

// ---------------- prologue: bf16 conversions into workspace ----------------
// ws layout (ushorts): wb[49152] | pwb[16384] | rpeb[240*384] | tvt[4*32*240]
__global__ void wa_prep(const float* __restrict__ qkv_w,
                        const float* __restrict__ rpe,
                        const float* __restrict__ proj_w,
                        ushort* __restrict__ wb, ushort* __restrict__ pwb,
                        ushort* __restrict__ rpeb, ushort* __restrict__ tvt){
  int t = blockIdx.x * 256 + threadIdx.x;
  if (t < 49152) wb[t] = f2bf(qkv_w[t]);
  if (t < 16384) pwb[t] = f2bf(proj_w[t]);
  if (t < 92160){                 // rpeb [240][384] in [3,H,32] packing;
    int r = t / 384, c = t % 384; // source table is [H,96]=[H][3][32] packing
    int part = c >> 7, rem = c & 127, h = rem >> 5, cc = rem & 31;
    int srcc = h * 96 + part * 32 + cc;
    float v = (r < 225) ? rpe[r * 384 + srcc] * ((part == 0) ? SCALE : 1.0f) : 0.f;
    rpeb[t] = f2bf(v);
  }
  if (t < 30720){                 // tvt [h][c 32][r 240]  (v_rpe^T)
    int r = t % 240, hc = t / 240;
    int h = hc >> 5, c = hc & 31;
    float v = (r < 225) ? rpe[r * 384 + h * 96 + 64 + c] : 0.f;
    tvt[t] = f2bf(v);
  }
}

// ---------------- main fused kernel ----------------
__global__ __launch_bounds__(512, 2) void wa_attn(
    const float* __restrict__ x, const float* __restrict__ mask,
    const float* __restrict__ qkv_b, const float* __restrict__ proj_b,
    const ushort* __restrict__ wb, const ushort* __restrict__ pwb,
    const ushort* __restrict__ rpeb, const ushort* __restrict__ tvt,
    float* __restrict__ out)
{
  __shared__ __align__(16) ushort sm[81664];      // 163328 B of 163840
  ushort* xs  = sm;               // [128][136] bf16 x
  ushort* qs  = sm + 17408;       // [128][52]  q (pre-scaled)
  ushort* ks  = sm + 24064;       // [128][52]  k
  ushort* vts = sm + 30720;       // [32][136]  v transposed [c][token]
  ushort* uvs = sm + 35072;       // [128][228] U_q / V_k / W overlay
  ushort* ps  = sm + 64256;       // [128][136] p (softmax), later att_out

  const int tid  = threadIdx.x;
  const int lane = tid & 63;
  const int wv   = tid >> 6;                      // 0..7
  const int m16  = lane & 15;
  const int q4   = lane >> 4;
  const int b    = blockIdx.x;
  const int wi   = b & 127;                       // window index for mask
  const int row0 = wv * 16;                       // this wave's M band
  const int rb   = row0 + q4 * 4;                 // this lane's 4 C/D rows
  const float* mrow = mask + (size_t)wi * 16384;

  // ---- P0: stage x -> bf16 LDS (4 threads per row)
  {
    int r = tid >> 2, qt = tid & 3;
    const float* src = x + (size_t)b * 16384 + r * 128 + qt * 32;
    ushort* dst = xs + r * 136 + qt * 32;
#pragma unroll
    for (int it = 0; it < 8; ++it){
      float4 f = *(const float4*)(src + it * 4);
      dst[it*4+0] = f2bf(f.x); dst[it*4+1] = f2bf(f.y);
      dst[it*4+2] = f2bf(f.z); dst[it*4+3] = f2bf(f.w);
    }
  }
  // ---- mask prefetch: head-invariant, keep in 32 VGPRs for the whole block.
  // Issued before the barrier so HBM/L2 latency overlaps P0 completion.
  float mv[8][4];
#pragma unroll
  for (int nt = 0; nt < 8; ++nt)
#pragma unroll
    for (int r = 0; r < 4; ++r)
      mv[nt][r] = mrow[(rb + r) * 128 + nt * 16 + m16];
  __syncthreads();

  f32x4 ao[4][2];                                 // per-head attn-out accum

#pragma unroll
  for (int h = 0; h < 4; ++h){
    // ---- P1: qkv GEMM  [16,128]@[128,96] for head h (per wave band)
    {
      f32x4 aqk[6];
#pragma unroll
      for (int nt = 0; nt < 6; ++nt) aqk[nt] = f32x4{0.f,0.f,0.f,0.f};
#pragma unroll
      for (int kk = 0; kk < 4; ++kk){
        bf16x8 a = ld16(xs + (row0 + m16)*136 + kk*32 + q4*8);
#pragma unroll
        for (int nt = 0; nt < 6; ++nt){
          int obase = (nt >> 1)*128 + h*32 + (nt & 1)*16;
          bf16x8 bf = ld16(wb + (obase + m16)*128 + kk*32 + q4*8);
          aqk[nt] = mfma16(a, bf, aqk[nt]);
        }
      }
#pragma unroll
      for (int nt = 0; nt < 6; ++nt){
        int part = nt >> 1;
        int colb = (nt & 1)*16 + m16;
        float bias = qkv_b[part*128 + h*32 + colb];
#pragma unroll
        for (int r = 0; r < 4; ++r){
          float v = aqk[nt][r] + bias;
          if (part == 0)      qs[(rb+r)*52 + colb] = f2bf(v * SCALE);
          else if (part == 1) ks[(rb+r)*52 + colb] = f2bf(v);
          else                vts[colb*136 + rb + r] = f2bf(v);
        }
      }
    }
    // ---- P2: U_q[i,r] = q[i,:]·k_rpe[r,:]   (own-band rows only)
    bf16x8 afq = ld8(qs + (row0 + m16)*52 + q4*8);
#pragma unroll
    for (int nt = 0; nt < 15; ++nt){
      bf16x8 bf = ld16(rpeb + (nt*16 + m16)*384 + 128 + h*32 + q4*8);
      f32x4 d = mfma16(afq, bf, f32x4{0.f,0.f,0.f,0.f});
      int col = nt*16 + m16;
      if (col < 225){
#pragma unroll
        for (int r = 0; r < 4; ++r) uvs[(rb+r)*228 + col] = f2bf(d[r]);
      }
    }
    __syncthreads();   // (A) qkv + U_q visible

    // ---- P3: qk GEMM + assembly pass A (mask regs + U_q gather)
    f32x4 S[8];
#pragma unroll
    for (int nt = 0; nt < 8; ++nt){
      bf16x8 bk = ld8(ks + (nt*16 + m16)*52 + q4*8);
      S[nt] = mfma16(afq, bk, f32x4{0.f,0.f,0.f,0.f});
    }
#pragma unroll
    for (int nt = 0; nt < 8; ++nt){
      int jp = (nt*16 + m16) >> 1;
#pragma unroll
      for (int r = 0; r < 4; ++r){
        int i = rb + r;
        S[nt][r] += mv[nt][r] + bf2f(uvs[i*228 + relidx(i >> 1, jp)]);
      }
    }
    // ---- P4: V_k[j,r] = k[j,:]·(scale·q_rpe[r,:])  (own-band rows; disjoint)
    {
      bf16x8 afk = ld8(ks + (row0 + m16)*52 + q4*8);
#pragma unroll
      for (int nt = 0; nt < 15; ++nt){
        bf16x8 bf = ld16(rpeb + (nt*16 + m16)*384 + h*32 + q4*8);
        f32x4 d = mfma16(afk, bf, f32x4{0.f,0.f,0.f,0.f});
        int col = nt*16 + m16;
        if (col < 225){
#pragma unroll
          for (int r = 0; r < 4; ++r) uvs[(rb+r)*228 + col] = f2bf(d[r]);
        }
      }
    }
    __syncthreads();   // (B) V_k visible to all waves

    // ---- P5: pass B (V_k gather) + softmax + write p
#pragma unroll
    for (int nt = 0; nt < 8; ++nt){
      int j = nt*16 + m16, jp = j >> 1;
#pragma unroll
      for (int r = 0; r < 4; ++r)
        S[nt][r] += bf2f(uvs[j*228 + relidx((rb+r) >> 1, jp)]);
    }
#pragma unroll
    for (int r = 0; r < 4; ++r){
      float mx = S[0][r];
#pragma unroll
      for (int nt = 1; nt < 8; ++nt) mx = fmaxf(mx, S[nt][r]);
      mx = fmaxf(mx, __shfl_xor(mx, 1));
      mx = fmaxf(mx, __shfl_xor(mx, 2));
      mx = fmaxf(mx, __shfl_xor(mx, 4));
      mx = fmaxf(mx, __shfl_xor(mx, 8));
      float e[8]; float sum = 0.f;
#pragma unroll
      for (int nt = 0; nt < 8; ++nt){
        e[nt] = exp2f((S[nt][r] - mx) * 1.44269504089f); sum += e[nt];
      }
      sum += __shfl_xor(sum, 1);
      sum += __shfl_xor(sum, 2);
      sum += __shfl_xor(sum, 4);
      sum += __shfl_xor(sum, 8);
      float inv = __builtin_amdgcn_rcpf(sum);
      int i = rb + r;
#pragma unroll
      for (int nt = 0; nt < 8; ++nt) ps[i*136 + nt*16 + m16] = f2bf(e[nt] * inv);
    }
    __syncthreads();   // (C) p visible; uvs free for W

    // ---- P6: out1 = p @ v
#pragma unroll
    for (int nt = 0; nt < 2; ++nt) ao[h][nt] = f32x4{0.f,0.f,0.f,0.f};
#pragma unroll
    for (int kk = 0; kk < 4; ++kk){
      bf16x8 ap = ld16(ps + (row0 + m16)*136 + kk*32 + q4*8);
#pragma unroll
      for (int nt = 0; nt < 2; ++nt){
        bf16x8 bv = ld16(vts + (nt*16 + m16)*136 + kk*32 + q4*8);
        ao[h][nt] = mfma16(ap, bv, ao[h][nt]);
      }
    }
    // ---- P7: W[i,r] = p2 scatter (injective per row -> plain writes)
    {
      uint* uz = (uint*)uvs;
#pragma unroll
      for (int it = 0; it < 29; ++it){            // 14592 uints
        int idx = it*512 + tid;
        if (idx < 14592) uz[idx] = 0;
      }
    }
    __syncthreads();   // (D) zeros done
#pragma unroll
    for (int it = 0; it < 16; ++it){
      int flat = it*512 + tid;
      int i = flat >> 6, jp = flat & 63;
      uint pp = *(const uint*)(ps + i*136 + jp*2);
      float p2 = bf2f((ushort)(pp & 0xFFFFu)) + bf2f((ushort)(pp >> 16));
      uvs[i*228 + relidx(i >> 1, jp)] = f2bf(p2);
    }
    __syncthreads();   // (E) W done
    // out2 = W @ Tv : 7 MFMA K-steps (r=0..223) + scalar fixup r=224
#pragma unroll
    for (int kk = 0; kk < 7; ++kk){
      bf16x8 aw = ld8(uvs + (row0 + m16)*228 + kk*32 + q4*8);
#pragma unroll
      for (int nt = 0; nt < 2; ++nt){
        bf16x8 bt = ld16(tvt + (h*32 + nt*16 + m16)*240 + kk*32 + q4*8);
        ao[h][nt] = mfma16(aw, bt, ao[h][nt]);
      }
    }
#pragma unroll
    for (int nt = 0; nt < 2; ++nt){
      float tvv = bf2f(tvt[(h*32 + nt*16 + m16)*240 + 224]);
#pragma unroll
      for (int r = 0; r < 4; ++r)
        ao[h][nt][r] += bf2f(uvs[(rb+r)*228 + 224]) * tvv;
    }
  } // heads

  // ---- P8: stage att_out (own rows, own wave) then proj GEMM
#pragma unroll
  for (int h = 0; h < 4; ++h)
#pragma unroll
    for (int nt = 0; nt < 2; ++nt){
      int col = h*32 + nt*16 + m16;
#pragma unroll
      for (int r = 0; r < 4; ++r) ps[(rb+r)*136 + col] = f2bf(ao[h][nt][r]);
    }
  // same-wave write->read: compiler inserts lgkmcnt; no barrier needed
  f32x4 po[8];
#pragma unroll
  for (int nt = 0; nt < 8; ++nt) po[nt] = f32x4{0.f,0.f,0.f,0.f};
#pragma unroll
  for (int kk = 0; kk < 4; ++kk){
    bf16x8 aA = ld16(ps + (row0 + m16)*136 + kk*32 + q4*8);
#pragma unroll
    for (int nt = 0; nt < 8; ++nt){
      bf16x8 bw = ld16(pwb + (nt*16 + m16)*128 + kk*32 + q4*8);
      po[nt] = mfma16(aA, bw, po[nt]);
    }
  }
  float* outb = out + (size_t)b * 16384;
#pragma unroll
  for (int nt = 0; nt < 8; ++nt){
    int o = nt*16 + m16;
    float bias = proj_b[o];
#pragma unroll
    for (int r = 0; r < 4; ++r) outb[(rb+r)*128 + o] = po[nt][r] + bias;
  }
}

extern "C" void kernel_launch(void* const* d_in, const int* in_sizes, int n_in,
                              void* d_out, int out_size, void* d_ws, size_t ws_size,
                              hipStream_t stream){
  (void)in_sizes; (void)n_in; (void)out_size; (void)ws_size;
  const float* x      = (const float*)d_in[0];
  const float* mask   = (const float*)d_in[1];
  const float* qkv_w  = (const float*)d_in[2];
  const float* qkv_b  = (const float*)d_in[3];
  const float* rpe    = (const float*)d_in[4];
  const float* proj_w = (const float*)d_in[5];
  const float* proj_b = (const float*)d_in[6];

  ushort* wb   = (ushort*)d_ws;            // 49152
  ushort* pwb  = wb + 49152;               // 16384
  ushort* rpeb = pwb + 16384;              // 240*384 = 92160
  ushort* tvt  = rpeb + 92160;             // 4*32*240 = 30720  (total 376832 B)

  wa_prep<<<360, 256, 0, stream>>>(qkv_w, rpe, proj_w, wb, pwb, rpeb, tvt);
  wa_attn<<<2048, 512, 0, stream>>>(x, mask, qkv_b, proj_b, wb, pwb, rpeb, tvt,
                                    (float*)d_out);
}

// Round 3
// 1475.590 us; speedup vs baseline: 1.2185x; 1.2185x over previous
//
#include <hip/hip_runtime.h>

// WindowAttention fused kernel for MI355X (gfx950).
// R3: fix the R2 spill regression. R2 (512 thr, __launch_bounds__(512,2))
// let the allocator cut VGPRs to 128 chasing occupancy that LDS (163KB ->
// 1 block/CU -> 8 waves -> 2 waves/SIMD) can never provide; per-thread live
// state (~140 regs) spilled to scratch: FETCH +770MB, WRITE +410MB, 1656us.
// Fix: amdgpu_waves_per_eu(2,2) pins the budget at 256 VGPR/wave (2 waves/
// SIMD is the LDS-imposed ceiling anyway), and the head-invariant mask regs
// (32 always-live VGPRs) go back to per-head loads issued at the top of P3 so
// L2 latency hides under the 8 qk MFMAs.
//
// Structure (from verified R1, re-banded): one workgroup per window block b
// (grid=2048), 512 threads = 8 waves, each wave owns a 16-row band.
// Fully fused: qkv GEMM -> per-head scores (qk MFMA + rpe via 225-table
// GEMM+gather) -> softmax -> p@v MFMA + p@v_rpe via scatter+GEMM -> proj GEMM.
// All matmuls bf16 MFMA 16x16x32, fp32 accumulate.
//
// rpe_table head packing is [H,96]->split(3) (q_rpe=h*96+0..31,
// k_rpe=h*96+32.., v_rpe=h*96+64..), NOT the qkv [3,H,32] packing. Permute in
// wa_prep so the main kernel's [3,H,32] view stays unchanged.

#define SCALE 0.17677669529663687f   // 32^-0.5

typedef __attribute__((ext_vector_type(8))) __bf16 bf16x8;
typedef __attribute__((ext_vector_type(4))) float  f32x4;

__device__ __forceinline__ float bf2f(ushort u){
  union { unsigned int i; float f; } v; v.i = ((unsigned int)u) << 16; return v.f;
}
__device__ __forceinline__ ushort f2bf(float f){
  union { float f; unsigned int i; } v; v.f = f;
  unsigned int r = v.i + 0x7FFFu + ((v.i >> 16) & 1u);   // RNE
  return (ushort)(r >> 16);
}
__device__ __forceinline__ bf16x8 ld16(const ushort* p){          // 16B-aligned
  int4 v = *(const int4*)p;
  return __builtin_bit_cast(bf16x8, v);
}
__device__ __forceinline__ bf16x8 ld8(const ushort* p){           // 8B-aligned
  int2 lo = *(const int2*)p;
  int2 hi = *(const int2*)(p + 4);
  int4 v = make_int4(lo.x, lo.y, hi.x, hi.y);
  return __builtin_bit_cast(bf16x8, v);
}
__device__ __forceinline__ f32x4 mfma16(bf16x8 a, bf16x8 b, f32x4 c){
  return __builtin_amdgcn_mfma_f32_16x16x32_bf16(a, b, c, 0, 0, 0);
}
// REL_IDX computed on the fly: ip,jp in [0,64) positions of the 8x8 window
__device__ __forceinline__ int relidx(int ip, int jp){
  return ((ip >> 3) - (jp >> 3) + 7) * 15 + ((ip & 7) - (jp & 7) + 7);
}

// ---------------- prologue: bf16 conversions into workspace ----------------
// ws layout (ushorts): wb[49152] | pwb[16384] | rpeb[240*384] | tvt[4*32*240]
__global__ void wa_prep(const float* __restrict__ qkv_w,
                        const float* __restrict__ rpe,
                        const float* __restrict__ proj_w,
                        ushort* __restrict__ wb, ushort* __restrict__ pwb,
                        ushort* __restrict__ rpeb, ushort* __restrict__ tvt){
  int t = blockIdx.x * 256 + threadIdx.x;
  if (t < 49152) wb[t] = f2bf(qkv_w[t]);
  if (t < 16384) pwb[t] = f2bf(proj_w[t]);
  if (t < 92160){                 // rpeb [240][384] in [3,H,32] packing;
    int r = t / 384, c = t % 384; // source table is [H,96]=[H][3][32] packing
    int part = c >> 7, rem = c & 127, h = rem >> 5, cc = rem & 31;
    int srcc = h * 96 + part * 32 + cc;
    float v = (r < 225) ? rpe[r * 384 + srcc] * ((part == 0) ? SCALE : 1.0f) : 0.f;
    rpeb[t] = f2bf(v);
  }
  if (t < 30720){                 // tvt [h][c 32][r 240]  (v_rpe^T)
    int r = t % 240, hc = t / 240;
    int h = hc >> 5, c = hc & 31;
    float v = (r < 225) ? rpe[r * 384 + h * 96 + 64 + c] : 0.f;
    tvt[t] = f2bf(v);
  }
}

// ---------------- main fused kernel ----------------
__global__ __launch_bounds__(512) __attribute__((amdgpu_waves_per_eu(2, 2)))
void wa_attn(
    const float* __restrict__ x, const float* __restrict__ mask,
    const float* __restrict__ qkv_b, const float* __restrict__ proj_b,
    const ushort* __restrict__ wb, const ushort* __restrict__ pwb,
    const ushort* __restrict__ rpeb, const ushort* __restrict__ tvt,
    float* __restrict__ out)
{
  __shared__ __align__(16) ushort sm[81664];      // 163328 B of 163840
  ushort* xs  = sm;               // [128][136] bf16 x
  ushort* qs  = sm + 17408;       // [128][52]  q (pre-scaled)
  ushort* ks  = sm + 24064;       // [128][52]  k
  ushort* vts = sm + 30720;       // [32][136]  v transposed [c][token]
  ushort* uvs = sm + 35072;       // [128][228] U_q / V_k / W overlay
  ushort* ps  = sm + 64256;       // [128][136] p (softmax), later att_out

  const int tid  = threadIdx.x;
  const int lane = tid & 63;
  const int wv   = tid >> 6;                      // 0..7
  const int m16  = lane & 15;
  const int q4   = lane >> 4;
  const int b    = blockIdx.x;
  const int wi   = b & 127;                       // window index for mask
  const int row0 = wv * 16;                       // this wave's M band
  const int rb   = row0 + q4 * 4;                 // this lane's 4 C/D rows
  const float* mrow = mask + (size_t)wi * 16384;

  // ---- P0: stage x -> bf16 LDS (4 threads per row)
  {
    int r = tid >> 2, qt = tid & 3;
    const float* src = x + (size_t)b * 16384 + r * 128 + qt * 32;
    ushort* dst = xs + r * 136 + qt * 32;
#pragma unroll
    for (int it = 0; it < 8; ++it){
      float4 f = *(const float4*)(src + it * 4);
      dst[it*4+0] = f2bf(f.x); dst[it*4+1] = f2bf(f.y);
      dst[it*4+2] = f2bf(f.z); dst[it*4+3] = f2bf(f.w);
    }
  }
  __syncthreads();

  f32x4 ao[4][2];                                 // per-head attn-out accum

#pragma unroll
  for (int h = 0; h < 4; ++h){
    // ---- P1: qkv GEMM  [16,128]@[128,96] for head h (per wave band)
    {
      f32x4 aqk[6];
#pragma unroll
      for (int nt = 0; nt < 6; ++nt) aqk[nt] = f32x4{0.f,0.f,0.f,0.f};
#pragma unroll
      for (int kk = 0; kk < 4; ++kk){
        bf16x8 a = ld16(xs + (row0 + m16)*136 + kk*32 + q4*8);
#pragma unroll
        for (int nt = 0; nt < 6; ++nt){
          int obase = (nt >> 1)*128 + h*32 + (nt & 1)*16;
          bf16x8 bf = ld16(wb + (obase + m16)*128 + kk*32 + q4*8);
          aqk[nt] = mfma16(a, bf, aqk[nt]);
        }
      }
#pragma unroll
      for (int nt = 0; nt < 6; ++nt){
        int part = nt >> 1;
        int colb = (nt & 1)*16 + m16;
        float bias = qkv_b[part*128 + h*32 + colb];
#pragma unroll
        for (int r = 0; r < 4; ++r){
          float v = aqk[nt][r] + bias;
          if (part == 0)      qs[(rb+r)*52 + colb] = f2bf(v * SCALE);
          else if (part == 1) ks[(rb+r)*52 + colb] = f2bf(v);
          else                vts[colb*136 + rb + r] = f2bf(v);
        }
      }
    }
    // ---- P2: U_q[i,r] = q[i,:]·k_rpe[r,:]   (own-band rows only)
    bf16x8 afq = ld8(qs + (row0 + m16)*52 + q4*8);
#pragma unroll
    for (int nt = 0; nt < 15; ++nt){
      bf16x8 bf = ld16(rpeb + (nt*16 + m16)*384 + 128 + h*32 + q4*8);
      f32x4 d = mfma16(afq, bf, f32x4{0.f,0.f,0.f,0.f});
      int col = nt*16 + m16;
      if (col < 225){
#pragma unroll
        for (int r = 0; r < 4; ++r) uvs[(rb+r)*228 + col] = f2bf(d[r]);
      }
    }
    __syncthreads();   // (A) qkv + U_q visible

    // ---- P3: mask prefetch (issues first; L2 latency hides under MFMAs),
    //          qk GEMM, then assembly pass A (mask + U_q gather)
    float mvl[8][4];
#pragma unroll
    for (int nt = 0; nt < 8; ++nt)
#pragma unroll
      for (int r = 0; r < 4; ++r)
        mvl[nt][r] = mrow[(rb + r) * 128 + nt * 16 + m16];
    f32x4 S[8];
#pragma unroll
    for (int nt = 0; nt < 8; ++nt){
      bf16x8 bk = ld8(ks + (nt*16 + m16)*52 + q4*8);
      S[nt] = mfma16(afq, bk, f32x4{0.f,0.f,0.f,0.f});
    }
#pragma unroll
    for (int nt = 0; nt < 8; ++nt){
      int jp = (nt*16 + m16) >> 1;
#pragma unroll
      for (int r = 0; r < 4; ++r){
        int i = rb + r;
        S[nt][r] += mvl[nt][r] + bf2f(uvs[i*228 + relidx(i >> 1, jp)]);
      }
    }
    // ---- P4: V_k[j,r] = k[j,:]·(scale·q_rpe[r,:])  (own-band rows; disjoint)
    {
      bf16x8 afk = ld8(ks + (row0 + m16)*52 + q4*8);
#pragma unroll
      for (int nt = 0; nt < 15; ++nt){
        bf16x8 bf = ld16(rpeb + (nt*16 + m16)*384 + h*32 + q4*8);
        f32x4 d = mfma16(afk, bf, f32x4{0.f,0.f,0.f,0.f});
        int col = nt*16 + m16;
        if (col < 225){
#pragma unroll
          for (int r = 0; r < 4; ++r) uvs[(rb+r)*228 + col] = f2bf(d[r]);
        }
      }
    }
    __syncthreads();   // (B) V_k visible to all waves

    // ---- P5: pass B (V_k gather) + softmax + write p
#pragma unroll
    for (int nt = 0; nt < 8; ++nt){
      int j = nt*16 + m16, jp = j >> 1;
#pragma unroll
      for (int r = 0; r < 4; ++r)
        S[nt][r] += bf2f(uvs[j*228 + relidx((rb+r) >> 1, jp)]);
    }
#pragma unroll
    for (int r = 0; r < 4; ++r){
      float mx = S[0][r];
#pragma unroll
      for (int nt = 1; nt < 8; ++nt) mx = fmaxf(mx, S[nt][r]);
      mx = fmaxf(mx, __shfl_xor(mx, 1));
      mx = fmaxf(mx, __shfl_xor(mx, 2));
      mx = fmaxf(mx, __shfl_xor(mx, 4));
      mx = fmaxf(mx, __shfl_xor(mx, 8));
      float e[8]; float sum = 0.f;
#pragma unroll
      for (int nt = 0; nt < 8; ++nt){
        e[nt] = exp2f((S[nt][r] - mx) * 1.44269504089f); sum += e[nt];
      }
      sum += __shfl_xor(sum, 1);
      sum += __shfl_xor(sum, 2);
      sum += __shfl_xor(sum, 4);
      sum += __shfl_xor(sum, 8);
      float inv = __builtin_amdgcn_rcpf(sum);
      int i = rb + r;
#pragma unroll
      for (int nt = 0; nt < 8; ++nt) ps[i*136 + nt*16 + m16] = f2bf(e[nt] * inv);
    }
    __syncthreads();   // (C) p visible; uvs free for W

    // ---- P6: out1 = p @ v
#pragma unroll
    for (int nt = 0; nt < 2; ++nt) ao[h][nt] = f32x4{0.f,0.f,0.f,0.f};
#pragma unroll
    for (int kk = 0; kk < 4; ++kk){
      bf16x8 ap = ld16(ps + (row0 + m16)*136 + kk*32 + q4*8);
#pragma unroll
      for (int nt = 0; nt < 2; ++nt){
        bf16x8 bv = ld16(vts + (nt*16 + m16)*136 + kk*32 + q4*8);
        ao[h][nt] = mfma16(ap, bv, ao[h][nt]);
      }
    }
    // ---- P7: W[i,r] = p2 scatter (injective per row -> plain writes)
    {
      uint* uz = (uint*)uvs;
#pragma unroll
      for (int it = 0; it < 29; ++it){            // 14592 uints
        int idx = it*512 + tid;
        if (idx < 14592) uz[idx] = 0;
      }
    }
    __syncthreads();   // (D) zeros done
#pragma unroll
    for (int it = 0; it < 16; ++it){
      int flat = it*512 + tid;
      int i = flat >> 6, jp = flat & 63;
      uint pp = *(const uint*)(ps + i*136 + jp*2);
      float p2 = bf2f((ushort)(pp & 0xFFFFu)) + bf2f((ushort)(pp >> 16));
      uvs[i*228 + relidx(i >> 1, jp)] = f2bf(p2);
    }
    __syncthreads();   // (E) W done
    // out2 = W @ Tv : 7 MFMA K-steps (r=0..223) + scalar fixup r=224
#pragma unroll
    for (int kk = 0; kk < 7; ++kk){
      bf16x8 aw = ld8(uvs + (row0 + m16)*228 + kk*32 + q4*8);
#pragma unroll
      for (int nt = 0; nt < 2; ++nt){
        bf16x8 bt = ld16(tvt + (h*32 + nt*16 + m16)*240 + kk*32 + q4*8);
        ao[h][nt] = mfma16(aw, bt, ao[h][nt]);
      }
    }
#pragma unroll
    for (int nt = 0; nt < 2; ++nt){
      float tvv = bf2f(tvt[(h*32 + nt*16 + m16)*240 + 224]);
#pragma unroll
      for (int r = 0; r < 4; ++r)
        ao[h][nt][r] += bf2f(uvs[(rb+r)*228 + 224]) * tvv;
    }
  } // heads

  // ---- P8: stage att_out (own rows, own wave) then proj GEMM
#pragma unroll
  for (int h = 0; h < 4; ++h)
#pragma unroll
    for (int nt = 0; nt < 2; ++nt){
      int col = h*32 + nt*16 + m16;
#pragma unroll
      for (int r = 0; r < 4; ++r) ps[(rb+r)*136 + col] = f2bf(ao[h][nt][r]);
    }
  // same-wave write->read: compiler inserts lgkmcnt; no barrier needed
  f32x4 po[8];
#pragma unroll
  for (int nt = 0; nt < 8; ++nt) po[nt] = f32x4{0.f,0.f,0.f,0.f};
#pragma unroll
  for (int kk = 0; kk < 4; ++kk){
    bf16x8 aA = ld16(ps + (row0 + m16)*136 + kk*32 + q4*8);
#pragma unroll
    for (int nt = 0; nt < 8; ++nt){
      bf16x8 bw = ld16(pwb + (nt*16 + m16)*128 + kk*32 + q4*8);
      po[nt] = mfma16(aA, bw, po[nt]);
    }
  }
  float* outb = out + (size_t)b * 16384;
#pragma unroll
  for (int nt = 0; nt < 8; ++nt){
    int o = nt*16 + m16;
    float bias = proj_b[o];
#pragma unroll
    for (int r = 0; r < 4; ++r) outb[(rb+r)*128 + o] = po[nt][r] + bias;
  }
}

extern "C" void kernel_launch(void* const* d_in, const int* in_sizes, int n_in,
                              void* d_out, int out_size, void* d_ws, size_t ws_size,
                              hipStream_t stream){
  (void)in_sizes; (void)n_in; (void)out_size; (void)ws_size;
  const float* x      = (const float*)d_in[0];
  const float* mask   = (const float*)d_in[1];
  const float* qkv_w  = (const float*)d_in[2];
  const float* qkv_b  = (const float*)d_in[3];
  const float* rpe    = (const float*)d_in[4];
  const float* proj_w = (const float*)d_in[5];
  const float* proj_b = (const float*)d_in[6];

  ushort* wb   = (ushort*)d_ws;            // 49152
  ushort* pwb  = wb + 49152;               // 16384
  ushort* rpeb = pwb + 16384;              // 240*384 = 92160
  ushort* tvt  = rpeb + 92160;             // 4*32*240 = 30720  (total 376832 B)

  wa_prep<<<360, 256, 0, stream>>>(qkv_w, rpe, proj_w, wb, pwb, rpeb, tvt);
  wa_attn<<<2048, 512, 0, stream>>>(x, mask, qkv_b, proj_b, wb, pwb, rpeb, tvt,
                                    (float*)d_out);
}

// Round 4
// 1393.087 us; speedup vs baseline: 1.2907x; 1.0592x over previous
//
#include <hip/hip_runtime.h>

// WindowAttention fused kernel for MI355X (gfx950).
// R4: fit the 512-thread kernel into the 128-arch-VGPR budget structurally.
// Evidence R2/R3: allocator pins 128 VGPRs for 512-thr blocks; cross-phase
// live state (ao[4][2] across the fully-unrolled 4-head body) spilled to
// scratch, whose traffic (F+672MB/W+296MB vs R1) also evicted the L3-resident
// mask/tables. Changes:
//  1. proj GEMM folded per-head: po[8] accumulates att_h @ proj_w[:,h*32:]
//     at each head's end (att_h staged through the dead, wave-private qs
//     region). ao[4][2] -> ao[2]; old P8 staging deleted. Same MFMA count.
//  2. head loop NOT unrolled (nothing h-indexed remains) -> short register
//     ranges, 1/4 the I$ footprint.
//  3. P7 (W zero/scatter/W@Tv) made wave-private (own 16-row band): barriers
//     D,E deleted; new barrier F at head end protects vts (P6 reads all rows)
//     from next head's P1 writes. Barriers/head 5 -> 4.
// Structure: one workgroup per window block b (grid=2048), 512 thr = 8 waves,
// each wave owns a 16-row band. Fully fused qkv -> scores(qk + rpe via
// 225-table GEMM+gather) -> softmax -> p@v + p@v_rpe(scatter+GEMM) -> proj.
// All matmuls bf16 MFMA 16x16x32, fp32 accumulate.
//
// rpe_table head packing is [H,96]->split(3); permuted in wa_prep so the main
// kernel sees [3,H,32].

#define SCALE 0.17677669529663687f   // 32^-0.5

typedef __attribute__((ext_vector_type(8))) __bf16 bf16x8;
typedef __attribute__((ext_vector_type(4))) float  f32x4;

__device__ __forceinline__ float bf2f(ushort u){
  union { unsigned int i; float f; } v; v.i = ((unsigned int)u) << 16; return v.f;
}
__device__ __forceinline__ ushort f2bf(float f){
  union { float f; unsigned int i; } v; v.f = f;
  unsigned int r = v.i + 0x7FFFu + ((v.i >> 16) & 1u);   // RNE
  return (ushort)(r >> 16);
}
__device__ __forceinline__ bf16x8 ld16(const ushort* p){          // 16B-aligned
  int4 v = *(const int4*)p;
  return __builtin_bit_cast(bf16x8, v);
}
__device__ __forceinline__ bf16x8 ld8(const ushort* p){           // 8B-aligned
  int2 lo = *(const int2*)p;
  int2 hi = *(const int2*)(p + 4);
  int4 v = make_int4(lo.x, lo.y, hi.x, hi.y);
  return __builtin_bit_cast(bf16x8, v);
}
__device__ __forceinline__ f32x4 mfma16(bf16x8 a, bf16x8 b, f32x4 c){
  return __builtin_amdgcn_mfma_f32_16x16x32_bf16(a, b, c, 0, 0, 0);
}
// REL_IDX computed on the fly: ip,jp in [0,64) positions of the 8x8 window
__device__ __forceinline__ int relidx(int ip, int jp){
  return ((ip >> 3) - (jp >> 3) + 7) * 15 + ((ip & 7) - (jp & 7) + 7);
}

// ---------------- prologue: bf16 conversions into workspace ----------------
// ws layout (ushorts): wb[49152] | pwb[16384] | rpeb[240*384] | tvt[4*32*240]
__global__ void wa_prep(const float* __restrict__ qkv_w,
                        const float* __restrict__ rpe,
                        const float* __restrict__ proj_w,
                        ushort* __restrict__ wb, ushort* __restrict__ pwb,
                        ushort* __restrict__ rpeb, ushort* __restrict__ tvt){
  int t = blockIdx.x * 256 + threadIdx.x;
  if (t < 49152) wb[t] = f2bf(qkv_w[t]);
  if (t < 16384) pwb[t] = f2bf(proj_w[t]);
  if (t < 92160){                 // rpeb [240][384] in [3,H,32] packing;
    int r = t / 384, c = t % 384; // source table is [H,96]=[H][3][32] packing
    int part = c >> 7, rem = c & 127, h = rem >> 5, cc = rem & 31;
    int srcc = h * 96 + part * 32 + cc;
    float v = (r < 225) ? rpe[r * 384 + srcc] * ((part == 0) ? SCALE : 1.0f) : 0.f;
    rpeb[t] = f2bf(v);
  }
  if (t < 30720){                 // tvt [h][c 32][r 240]  (v_rpe^T)
    int r = t % 240, hc = t / 240;
    int h = hc >> 5, c = hc & 31;
    float v = (r < 225) ? rpe[r * 384 + h * 96 + 64 + c] : 0.f;
    tvt[t] = f2bf(v);
  }
}

// ---------------- main fused kernel ----------------
__global__ __launch_bounds__(512) __attribute__((amdgpu_waves_per_eu(2, 2)))
void wa_attn(
    const float* __restrict__ x, const float* __restrict__ mask,
    const float* __restrict__ qkv_b, const float* __restrict__ proj_b,
    const ushort* __restrict__ wb, const ushort* __restrict__ pwb,
    const ushort* __restrict__ rpeb, const ushort* __restrict__ tvt,
    float* __restrict__ out)
{
  __shared__ __align__(16) ushort sm[81664];      // 163328 B of 163840
  ushort* xs  = sm;               // [128][136] bf16 x
  ushort* qs  = sm + 17408;       // [128][52]  q (pre-scaled); att_h staging
  ushort* ks  = sm + 24064;       // [128][52]  k
  ushort* vts = sm + 30720;       // [32][136]  v transposed [c][token]
  ushort* uvs = sm + 35072;       // [128][228] U_q / V_k / W overlay
  ushort* ps  = sm + 64256;       // [128][136] p (softmax)

  const int tid  = threadIdx.x;
  const int lane = tid & 63;
  const int wv   = tid >> 6;                      // 0..7
  const int m16  = lane & 15;
  const int q4   = lane >> 4;
  const int b    = blockIdx.x;
  const int wi   = b & 127;                       // window index for mask
  const int row0 = wv * 16;                       // this wave's M band
  const int rb   = row0 + q4 * 4;                 // this lane's 4 C/D rows
  const float* mrow = mask + (size_t)wi * 16384;

  // ---- P0: stage x -> bf16 LDS (4 threads per row)
  {
    int r = tid >> 2, qt = tid & 3;
    const float* src = x + (size_t)b * 16384 + r * 128 + qt * 32;
    ushort* dst = xs + r * 136 + qt * 32;
#pragma unroll
    for (int it = 0; it < 8; ++it){
      float4 f = *(const float4*)(src + it * 4);
      dst[it*4+0] = f2bf(f.x); dst[it*4+1] = f2bf(f.y);
      dst[it*4+2] = f2bf(f.z); dst[it*4+3] = f2bf(f.w);
    }
  }
  __syncthreads();

  f32x4 po[8];                                    // proj accumulators (whole loop)
#pragma unroll
  for (int nt = 0; nt < 8; ++nt) po[nt] = f32x4{0.f,0.f,0.f,0.f};

#pragma clang loop unroll(disable)
  for (int h = 0; h < 4; ++h){
    // ---- P1: qkv GEMM  [16,128]@[128,96] for head h (per wave band)
    {
      f32x4 aqk[6];
#pragma unroll
      for (int nt = 0; nt < 6; ++nt) aqk[nt] = f32x4{0.f,0.f,0.f,0.f};
#pragma unroll
      for (int kk = 0; kk < 4; ++kk){
        bf16x8 a = ld16(xs + (row0 + m16)*136 + kk*32 + q4*8);
#pragma unroll
        for (int nt = 0; nt < 6; ++nt){
          int obase = (nt >> 1)*128 + h*32 + (nt & 1)*16;
          bf16x8 bf = ld16(wb + (obase + m16)*128 + kk*32 + q4*8);
          aqk[nt] = mfma16(a, bf, aqk[nt]);
        }
      }
#pragma unroll
      for (int nt = 0; nt < 6; ++nt){
        int part = nt >> 1;
        int colb = (nt & 1)*16 + m16;
        float bias = qkv_b[part*128 + h*32 + colb];
#pragma unroll
        for (int r = 0; r < 4; ++r){
          float v = aqk[nt][r] + bias;
          if (part == 0)      qs[(rb+r)*52 + colb] = f2bf(v * SCALE);
          else if (part == 1) ks[(rb+r)*52 + colb] = f2bf(v);
          else                vts[colb*136 + rb + r] = f2bf(v);
        }
      }
    }
    // ---- P2: U_q[i,r] = q[i,:]·k_rpe[r,:]   (own-band rows only)
    bf16x8 afq = ld8(qs + (row0 + m16)*52 + q4*8);
#pragma unroll
    for (int nt = 0; nt < 15; ++nt){
      bf16x8 bf = ld16(rpeb + (nt*16 + m16)*384 + 128 + h*32 + q4*8);
      f32x4 d = mfma16(afq, bf, f32x4{0.f,0.f,0.f,0.f});
      int col = nt*16 + m16;
      if (col < 225){
#pragma unroll
        for (int r = 0; r < 4; ++r) uvs[(rb+r)*228 + col] = f2bf(d[r]);
      }
    }
    __syncthreads();   // (A) ks/vts (all bands) + own U_q visible

    // ---- P3: mask prefetch (issues first; latency hides under MFMAs),
    //          qk GEMM, then assembly pass A (mask + U_q gather, own rows)
    {
      float mvl[8][4];
#pragma unroll
      for (int nt = 0; nt < 8; ++nt)
#pragma unroll
        for (int r = 0; r < 4; ++r)
          mvl[nt][r] = mrow[(rb + r) * 128 + nt * 16 + m16];
      f32x4 S[8];
#pragma unroll
      for (int nt = 0; nt < 8; ++nt){
        bf16x8 bk = ld8(ks + (nt*16 + m16)*52 + q4*8);
        S[nt] = mfma16(afq, bk, f32x4{0.f,0.f,0.f,0.f});
      }
#pragma unroll
      for (int nt = 0; nt < 8; ++nt){
        int jp = (nt*16 + m16) >> 1;
#pragma unroll
        for (int r = 0; r < 4; ++r){
          int i = rb + r;
          S[nt][r] += mvl[nt][r] + bf2f(uvs[i*228 + relidx(i >> 1, jp)]);
        }
      }
      // ---- P4: V_k[j,r] = k[j,:]·(scale·q_rpe[r,:]) (own band; disjoint)
      {
        bf16x8 afk = ld8(ks + (row0 + m16)*52 + q4*8);
#pragma unroll
        for (int nt = 0; nt < 15; ++nt){
          bf16x8 bf = ld16(rpeb + (nt*16 + m16)*384 + h*32 + q4*8);
          f32x4 d = mfma16(afk, bf, f32x4{0.f,0.f,0.f,0.f});
          int col = nt*16 + m16;
          if (col < 225){
#pragma unroll
            for (int r = 0; r < 4; ++r) uvs[(rb+r)*228 + col] = f2bf(d[r]);
          }
        }
      }
      __syncthreads();   // (B) V_k (all bands) visible

      // ---- P5: pass B (V_k gather) + softmax + write p
#pragma unroll
      for (int nt = 0; nt < 8; ++nt){
        int j = nt*16 + m16, jp = j >> 1;
#pragma unroll
        for (int r = 0; r < 4; ++r)
          S[nt][r] += bf2f(uvs[j*228 + relidx((rb+r) >> 1, jp)]);
      }
#pragma unroll
      for (int r = 0; r < 4; ++r){
        float mx = S[0][r];
#pragma unroll
        for (int nt = 1; nt < 8; ++nt) mx = fmaxf(mx, S[nt][r]);
        mx = fmaxf(mx, __shfl_xor(mx, 1));
        mx = fmaxf(mx, __shfl_xor(mx, 2));
        mx = fmaxf(mx, __shfl_xor(mx, 4));
        mx = fmaxf(mx, __shfl_xor(mx, 8));
        float e[8]; float sum = 0.f;
#pragma unroll
        for (int nt = 0; nt < 8; ++nt){
          e[nt] = exp2f((S[nt][r] - mx) * 1.44269504089f); sum += e[nt];
        }
        sum += __shfl_xor(sum, 1);
        sum += __shfl_xor(sum, 2);
        sum += __shfl_xor(sum, 4);
        sum += __shfl_xor(sum, 8);
        float inv = __builtin_amdgcn_rcpf(sum);
        int i = rb + r;
#pragma unroll
        for (int nt = 0; nt < 8; ++nt) ps[i*136 + nt*16 + m16] = f2bf(e[nt] * inv);
      }
    } // S/mvl dead here
    __syncthreads();   // (C) all waves done reading uvs (pass B); W may start

    // ---- P6: out1 = p @ v  (ps own rows: own-wave write->read)
    f32x4 ao[2];
#pragma unroll
    for (int nt = 0; nt < 2; ++nt) ao[nt] = f32x4{0.f,0.f,0.f,0.f};
#pragma unroll
    for (int kk = 0; kk < 4; ++kk){
      bf16x8 ap = ld16(ps + (row0 + m16)*136 + kk*32 + q4*8);
#pragma unroll
      for (int nt = 0; nt < 2; ++nt){
        bf16x8 bv = ld16(vts + (nt*16 + m16)*136 + kk*32 + q4*8);
        ao[nt] = mfma16(ap, bv, ao[nt]);
      }
    }
    // ---- P7 (wave-private): zero own W band, scatter p2, W @ Tv
    {
      uint* base = (uint*)(uvs + row0*228);       // 16*228/2 = 1824 uints
#pragma unroll
      for (int it = 0; it < 29; ++it){
        int idx = it*64 + lane;
        if (idx < 1824) base[idx] = 0;
      }
    }
#pragma unroll
    for (int it = 0; it < 16; ++it){              // 16 rows x 64 jp
      int flat = it*64 + lane;
      int i = row0 + (flat >> 6), jp = flat & 63;
      uint pp = *(const uint*)(ps + i*136 + jp*2);
      float p2 = bf2f((ushort)(pp & 0xFFFFu)) + bf2f((ushort)(pp >> 16));
      uvs[i*228 + relidx(i >> 1, jp)] = f2bf(p2);
    }
    // out2 = W @ Tv : 7 MFMA K-steps (r=0..223) + scalar fixup r=224
    // (same-wave LDS write->read: in-order per wave, compiler waits lgkmcnt)
#pragma unroll
    for (int kk = 0; kk < 7; ++kk){
      bf16x8 aw = ld8(uvs + (row0 + m16)*228 + kk*32 + q4*8);
#pragma unroll
      for (int nt = 0; nt < 2; ++nt){
        bf16x8 bt = ld16(tvt + (h*32 + nt*16 + m16)*240 + kk*32 + q4*8);
        ao[nt] = mfma16(aw, bt, ao[nt]);
      }
    }
#pragma unroll
    for (int nt = 0; nt < 2; ++nt){
      float tvv = bf2f(tvt[(h*32 + nt*16 + m16)*240 + 224]);
#pragma unroll
      for (int r = 0; r < 4; ++r)
        ao[nt][r] += bf2f(uvs[(rb+r)*228 + 224]) * tvv;
    }
    // ---- proj partial: stage att_h via qs (wave-private rows), accumulate po
#pragma unroll
    for (int nt = 0; nt < 2; ++nt)
#pragma unroll
      for (int r = 0; r < 4; ++r)
        qs[(rb+r)*52 + nt*16 + m16] = f2bf(ao[nt][r]);
    {
      bf16x8 aA = ld8(qs + (row0 + m16)*52 + q4*8);   // own band, same wave
#pragma unroll
      for (int nt = 0; nt < 8; ++nt){
        bf16x8 bw = ld16(pwb + (nt*16 + m16)*128 + h*32 + q4*8);
        po[nt] = mfma16(aA, bw, po[nt]);
      }
    }
    __syncthreads();   // (F) protect vts/ks/qs from next head's P1 writes
  } // heads

  // ---- epilogue: out = po + bias
  float* outb = out + (size_t)b * 16384;
#pragma unroll
  for (int nt = 0; nt < 8; ++nt){
    int o = nt*16 + m16;
    float bias = proj_b[o];
#pragma unroll
    for (int r = 0; r < 4; ++r) outb[(rb+r)*128 + o] = po[nt][r] + bias;
  }
}

extern "C" void kernel_launch(void* const* d_in, const int* in_sizes, int n_in,
                              void* d_out, int out_size, void* d_ws, size_t ws_size,
                              hipStream_t stream){
  (void)in_sizes; (void)n_in; (void)out_size; (void)ws_size;
  const float* x      = (const float*)d_in[0];
  const float* mask   = (const float*)d_in[1];
  const float* qkv_w  = (const float*)d_in[2];
  const float* qkv_b  = (const float*)d_in[3];
  const float* rpe    = (const float*)d_in[4];
  const float* proj_w = (const float*)d_in[5];
  const float* proj_b = (const float*)d_in[6];

  ushort* wb   = (ushort*)d_ws;            // 49152
  ushort* pwb  = wb + 49152;               // 16384
  ushort* rpeb = pwb + 16384;              // 240*384 = 92160
  ushort* tvt  = rpeb + 92160;             // 4*32*240 = 30720  (total 376832 B)

  wa_prep<<<360, 256, 0, stream>>>(qkv_w, rpe, proj_w, wb, pwb, rpeb, tvt);
  wa_attn<<<2048, 512, 0, stream>>>(x, mask, qkv_b, proj_b, wb, pwb, rpeb, tvt,
                                    (float*)d_out);
}

// Round 5
// 892.265 us; speedup vs baseline: 2.0151x; 1.5613x over previous
//
#include <hip/hip_runtime.h>

// WindowAttention fused kernel for MI355X (gfx950).
// R5: kill residual spill + halve scalar-LDS traffic via layout.
//  - uvs is COLUMN-MAJOR [col 225][row 132-pad] during U_q/V_k phases:
//    MFMA C/D holds 4 rows of one col per lane -> P2/P4 write 15x b64
//    (was 60x u16); pass-A gather 16x b32 (rows rb,rb+1 share ip since rb
//    is even); pass-B 16 reads (value shared by 2 rows). W phase (P7)
//    reuses the buffer ROW-major as before (barrier C separates).
//  - mask loads become the MFMA C-init of the qk GEMM: deletes mvl[8][4]
//    (32 live VGPRs -> was the remaining spill driver) and 32 VALU adds.
//  - v-part of P1 written as b64; W zero-fill via uint4; qs/ks stride 52->44
//    to fund the uvs pad. LDS 160272 B (1 block/CU unchanged).
// Structure: one workgroup per window block b (grid=2048), 512 thr = 8 waves,
// each wave owns a 16-row band. Fully fused qkv -> scores(qk+rpe) -> softmax
// -> p@v + p@v_rpe(scatter+GEMM) -> proj (folded per-head). bf16 MFMA
// 16x16x32, fp32 accumulate.
// rpe_table head packing is [H,96]->split(3); permuted in wa_prep so the main
// kernel sees [3,H,32].

#define SCALE 0.17677669529663687f   // 32^-0.5

typedef __attribute__((ext_vector_type(8))) __bf16 bf16x8;
typedef __attribute__((ext_vector_type(4))) float  f32x4;

__device__ __forceinline__ float bf2f(ushort u){
  union { unsigned int i; float f; } v; v.i = ((unsigned int)u) << 16; return v.f;
}
__device__ __forceinline__ ushort f2bf(float f){
  union { float f; unsigned int i; } v; v.f = f;
  unsigned int r = v.i + 0x7FFFu + ((v.i >> 16) & 1u);   // RNE
  return (ushort)(r >> 16);
}
__device__ __forceinline__ bf16x8 ld16(const ushort* p){          // 16B-aligned
  int4 v = *(const int4*)p;
  return __builtin_bit_cast(bf16x8, v);
}
__device__ __forceinline__ bf16x8 ld8(const ushort* p){           // 8B-aligned
  int2 lo = *(const int2*)p;
  int2 hi = *(const int2*)(p + 4);
  int4 v = make_int4(lo.x, lo.y, hi.x, hi.y);
  return __builtin_bit_cast(bf16x8, v);
}
__device__ __forceinline__ f32x4 mfma16(bf16x8 a, bf16x8 b, f32x4 c){
  return __builtin_amdgcn_mfma_f32_16x16x32_bf16(a, b, c, 0, 0, 0);
}
// REL_IDX computed on the fly: ip,jp in [0,64) positions of the 8x8 window
__device__ __forceinline__ int relidx(int ip, int jp){
  return ((ip >> 3) - (jp >> 3) + 7) * 15 + ((ip & 7) - (jp & 7) + 7);
}

// ---------------- prologue: bf16 conversions into workspace ----------------
// ws layout (ushorts): wb[49152] | pwb[16384] | rpeb[240*384] | tvt[4*32*240]
__global__ void wa_prep(const float* __restrict__ qkv_w,
                        const float* __restrict__ rpe,
                        const float* __restrict__ proj_w,
                        ushort* __restrict__ wb, ushort* __restrict__ pwb,
                        ushort* __restrict__ rpeb, ushort* __restrict__ tvt){
  int t = blockIdx.x * 256 + threadIdx.x;
  if (t < 49152) wb[t] = f2bf(qkv_w[t]);
  if (t < 16384) pwb[t] = f2bf(proj_w[t]);
  if (t < 92160){                 // rpeb [240][384] in [3,H,32] packing;
    int r = t / 384, c = t % 384; // source table is [H,96]=[H][3][32] packing
    int part = c >> 7, rem = c & 127, h = rem >> 5, cc = rem & 31;
    int srcc = h * 96 + part * 32 + cc;
    float v = (r < 225) ? rpe[r * 384 + srcc] * ((part == 0) ? SCALE : 1.0f) : 0.f;
    rpeb[t] = f2bf(v);
  }
  if (t < 30720){                 // tvt [h][c 32][r 240]  (v_rpe^T)
    int r = t % 240, hc = t / 240;
    int h = hc >> 5, c = hc & 31;
    float v = (r < 225) ? rpe[r * 384 + h * 96 + 64 + c] : 0.f;
    tvt[t] = f2bf(v);
  }
}

// ---------------- main fused kernel ----------------
__global__ __launch_bounds__(512) void wa_attn(
    const float* __restrict__ x, const float* __restrict__ mask,
    const float* __restrict__ qkv_b, const float* __restrict__ proj_b,
    const ushort* __restrict__ wb, const ushort* __restrict__ pwb,
    const ushort* __restrict__ rpeb, const ushort* __restrict__ tvt,
    float* __restrict__ out)
{
  __shared__ __align__(16) ushort sm[80136];      // 160272 B
  ushort* xs  = sm;               // [128][136] bf16 x
  ushort* qs  = sm + 17408;       // [128][44]  q (pre-scaled); att_h staging
  ushort* ks  = sm + 23040;       // [128][44]  k
  ushort* vts = sm + 28672;       // [32][136]  v transposed [c][token]
  ushort* uvs = sm + 33024;       // U_q/V_k col-major [225][132] | W row-major [128][228]
  ushort* ps  = sm + 62728;       // [128][136] p (softmax)

  const int tid  = threadIdx.x;
  const int lane = tid & 63;
  const int wv   = tid >> 6;                      // 0..7
  const int m16  = lane & 15;
  const int q4   = lane >> 4;
  const int b    = blockIdx.x;
  const int wi   = b & 127;                       // window index for mask
  const int row0 = wv * 16;                       // this wave's M band
  const int rb   = row0 + q4 * 4;                 // this lane's 4 C/D rows (even)
  const int ip0  = rb >> 1;                       // window pos of rows rb,rb+1
  const float* mrow = mask + (size_t)wi * 16384;

  // ---- P0: stage x -> bf16 LDS (4 threads per row)
  {
    int r = tid >> 2, qt = tid & 3;
    const float* src = x + (size_t)b * 16384 + r * 128 + qt * 32;
    ushort* dst = xs + r * 136 + qt * 32;
#pragma unroll
    for (int it = 0; it < 8; ++it){
      float4 f = *(const float4*)(src + it * 4);
      dst[it*4+0] = f2bf(f.x); dst[it*4+1] = f2bf(f.y);
      dst[it*4+2] = f2bf(f.z); dst[it*4+3] = f2bf(f.w);
    }
  }
  __syncthreads();

  f32x4 po[8];                                    // proj accumulators
#pragma unroll
  for (int nt = 0; nt < 8; ++nt) po[nt] = f32x4{0.f,0.f,0.f,0.f};

#pragma clang loop unroll(disable)
  for (int h = 0; h < 4; ++h){
    // ---- P1: qkv GEMM  [16,128]@[128,96] for head h (per wave band)
    {
      f32x4 aqk[6];
#pragma unroll
      for (int nt = 0; nt < 6; ++nt) aqk[nt] = f32x4{0.f,0.f,0.f,0.f};
#pragma unroll
      for (int kk = 0; kk < 4; ++kk){
        bf16x8 a = ld16(xs + (row0 + m16)*136 + kk*32 + q4*8);
#pragma unroll
        for (int nt = 0; nt < 6; ++nt){
          int obase = (nt >> 1)*128 + h*32 + (nt & 1)*16;
          bf16x8 bf = ld16(wb + (obase + m16)*128 + kk*32 + q4*8);
          aqk[nt] = mfma16(a, bf, aqk[nt]);
        }
      }
#pragma unroll
      for (int nt = 0; nt < 6; ++nt){
        int part = nt >> 1;
        int colb = (nt & 1)*16 + m16;
        float bias = qkv_b[part*128 + h*32 + colb];
        float t0 = aqk[nt][0] + bias, t1 = aqk[nt][1] + bias;
        float t2 = aqk[nt][2] + bias, t3 = aqk[nt][3] + bias;
        if (part == 0){
          qs[(rb+0)*44 + colb] = f2bf(t0 * SCALE);
          qs[(rb+1)*44 + colb] = f2bf(t1 * SCALE);
          qs[(rb+2)*44 + colb] = f2bf(t2 * SCALE);
          qs[(rb+3)*44 + colb] = f2bf(t3 * SCALE);
        } else if (part == 1){
          ks[(rb+0)*44 + colb] = f2bf(t0);
          ks[(rb+1)*44 + colb] = f2bf(t1);
          ks[(rb+2)*44 + colb] = f2bf(t2);
          ks[(rb+3)*44 + colb] = f2bf(t3);
        } else {                                  // v^T: 4 consecutive tokens
          uint lo = (uint)f2bf(t0) | ((uint)f2bf(t1) << 16);
          uint hi = (uint)f2bf(t2) | ((uint)f2bf(t3) << 16);
          *(uint2*)(vts + colb*136 + rb) = make_uint2(lo, hi);
        }
      }
    }
    // ---- P2: U_q[col][row] = q[i,:]·k_rpe[col,:]  (own rows; col-major b64)
    bf16x8 afq = ld8(qs + (row0 + m16)*44 + q4*8);
#pragma unroll
    for (int nt = 0; nt < 15; ++nt){
      bf16x8 bf = ld16(rpeb + (nt*16 + m16)*384 + 128 + h*32 + q4*8);
      f32x4 d = mfma16(afq, bf, f32x4{0.f,0.f,0.f,0.f});
      int col = nt*16 + m16;
      if (col < 225){
        uint lo = (uint)f2bf(d[0]) | ((uint)f2bf(d[1]) << 16);
        uint hi = (uint)f2bf(d[2]) | ((uint)f2bf(d[3]) << 16);
        *(uint2*)(uvs + col*132 + rb) = make_uint2(lo, hi);
      }
    }
    __syncthreads();   // (A) ks/vts (all bands) visible; own U_q same-wave

    // ---- P3: qk GEMM with mask as C-init, then U_q gather (own rows)
    {
      f32x4 S[8];
#pragma unroll
      for (int nt = 0; nt < 8; ++nt)
#pragma unroll
        for (int r = 0; r < 4; ++r)
          S[nt][r] = mrow[(rb + r) * 128 + nt * 16 + m16];
#pragma unroll
      for (int nt = 0; nt < 8; ++nt){
        bf16x8 bk = ld8(ks + (nt*16 + m16)*44 + q4*8);
        S[nt] = mfma16(afq, bk, S[nt]);
      }
#pragma unroll
      for (int nt = 0; nt < 8; ++nt){
        int jp = (nt*16 + m16) >> 1;
        uint u0 = *(const uint*)(uvs + relidx(ip0,     jp)*132 + rb);
        uint u1 = *(const uint*)(uvs + relidx(ip0 + 1, jp)*132 + rb + 2);
        S[nt][0] += bf2f((ushort)(u0 & 0xFFFFu));
        S[nt][1] += bf2f((ushort)(u0 >> 16));
        S[nt][2] += bf2f((ushort)(u1 & 0xFFFFu));
        S[nt][3] += bf2f((ushort)(u1 >> 16));
      }
      // ---- P4: V_k[col][row] = k[j,:]·(scale·q_rpe[col,:]) (own rows)
      {
        bf16x8 afk = ld8(ks + (row0 + m16)*44 + q4*8);
#pragma unroll
        for (int nt = 0; nt < 15; ++nt){
          bf16x8 bf = ld16(rpeb + (nt*16 + m16)*384 + h*32 + q4*8);
          f32x4 d = mfma16(afk, bf, f32x4{0.f,0.f,0.f,0.f});
          int col = nt*16 + m16;
          if (col < 225){
            uint lo = (uint)f2bf(d[0]) | ((uint)f2bf(d[1]) << 16);
            uint hi = (uint)f2bf(d[2]) | ((uint)f2bf(d[3]) << 16);
            *(uint2*)(uvs + col*132 + rb) = make_uint2(lo, hi);
          }
        }
      }
      __syncthreads();   // (B) V_k (all bands) visible

      // ---- P5: pass B (V_k gather; one value serves 2 rows) + softmax
#pragma unroll
      for (int nt = 0; nt < 8; ++nt){
        int j = nt*16 + m16, jp = j >> 1;
        float v0 = bf2f(uvs[relidx(ip0,     jp)*132 + j]);
        float v1 = bf2f(uvs[relidx(ip0 + 1, jp)*132 + j]);
        S[nt][0] += v0; S[nt][1] += v0;
        S[nt][2] += v1; S[nt][3] += v1;
      }
#pragma unroll
      for (int r = 0; r < 4; ++r){
        float mx = S[0][r];
#pragma unroll
        for (int nt = 1; nt < 8; ++nt) mx = fmaxf(mx, S[nt][r]);
        mx = fmaxf(mx, __shfl_xor(mx, 1));
        mx = fmaxf(mx, __shfl_xor(mx, 2));
        mx = fmaxf(mx, __shfl_xor(mx, 4));
        mx = fmaxf(mx, __shfl_xor(mx, 8));
        float e[8]; float sum = 0.f;
#pragma unroll
        for (int nt = 0; nt < 8; ++nt){
          e[nt] = exp2f((S[nt][r] - mx) * 1.44269504089f); sum += e[nt];
        }
        sum += __shfl_xor(sum, 1);
        sum += __shfl_xor(sum, 2);
        sum += __shfl_xor(sum, 4);
        sum += __shfl_xor(sum, 8);
        float inv = __builtin_amdgcn_rcpf(sum);
        int i = rb + r;
#pragma unroll
        for (int nt = 0; nt < 8; ++nt) ps[i*136 + nt*16 + m16] = f2bf(e[nt] * inv);
      }
    } // S dead here
    __syncthreads();   // (C) all waves done reading uvs (pass B); W may start

    // ---- P6: out1 = p @ v  (ps own rows: own-wave write->read)
    f32x4 ao[2];
#pragma unroll
    for (int nt = 0; nt < 2; ++nt) ao[nt] = f32x4{0.f,0.f,0.f,0.f};
#pragma unroll
    for (int kk = 0; kk < 4; ++kk){
      bf16x8 ap = ld16(ps + (row0 + m16)*136 + kk*32 + q4*8);
#pragma unroll
      for (int nt = 0; nt < 2; ++nt){
        bf16x8 bv = ld16(vts + (nt*16 + m16)*136 + kk*32 + q4*8);
        ao[nt] = mfma16(ap, bv, ao[nt]);
      }
    }
    // ---- P7 (wave-private): zero own W band (uint4), scatter p2, W @ Tv
    {
      uint4* zb = (uint4*)(uvs + row0*228);       // 16*228*2 B = 456 uint4
#pragma unroll
      for (int it = 0; it < 8; ++it){
        int idx = it*64 + lane;
        if (idx < 456) zb[idx] = make_uint4(0,0,0,0);
      }
    }
#pragma unroll
    for (int it = 0; it < 16; ++it){              // own 16 rows x 64 jp
      int i = row0 + it, jp = lane;
      uint pp = *(const uint*)(ps + i*136 + jp*2);
      float p2 = bf2f((ushort)(pp & 0xFFFFu)) + bf2f((ushort)(pp >> 16));
      uvs[i*228 + relidx(i >> 1, jp)] = f2bf(p2);
    }
    // out2 = W @ Tv : 7 MFMA K-steps (r=0..223) + scalar fixup r=224
    // (same-wave LDS write->read: in-order per wave, compiler waits lgkmcnt)
#pragma unroll
    for (int kk = 0; kk < 7; ++kk){
      bf16x8 aw = ld8(uvs + (row0 + m16)*228 + kk*32 + q4*8);
#pragma unroll
      for (int nt = 0; nt < 2; ++nt){
        bf16x8 bt = ld16(tvt + (h*32 + nt*16 + m16)*240 + kk*32 + q4*8);
        ao[nt] = mfma16(aw, bt, ao[nt]);
      }
    }
#pragma unroll
    for (int nt = 0; nt < 2; ++nt){
      float tvv = bf2f(tvt[(h*32 + nt*16 + m16)*240 + 224]);
#pragma unroll
      for (int r = 0; r < 4; ++r)
        ao[nt][r] += bf2f(uvs[(rb+r)*228 + 224]) * tvv;
    }
    // ---- proj partial: stage att_h via qs (wave-private rows), accumulate po
#pragma unroll
    for (int nt = 0; nt < 2; ++nt)
#pragma unroll
      for (int r = 0; r < 4; ++r)
        qs[(rb+r)*44 + nt*16 + m16] = f2bf(ao[nt][r]);
    {
      bf16x8 aA = ld8(qs + (row0 + m16)*44 + q4*8);   // own band, same wave
#pragma unroll
      for (int nt = 0; nt < 8; ++nt){
        bf16x8 bw = ld16(pwb + (nt*16 + m16)*128 + h*32 + q4*8);
        po[nt] = mfma16(aA, bw, po[nt]);
      }
    }
    __syncthreads();   // (F) protect vts/ks/qs from next head's P1 writes
  } // heads

  // ---- epilogue: out = po + bias
  float* outb = out + (size_t)b * 16384;
#pragma unroll
  for (int nt = 0; nt < 8; ++nt){
    int o = nt*16 + m16;
    float bias = proj_b[o];
#pragma unroll
    for (int r = 0; r < 4; ++r) outb[(rb+r)*128 + o] = po[nt][r] + bias;
  }
}

extern "C" void kernel_launch(void* const* d_in, const int* in_sizes, int n_in,
                              void* d_out, int out_size, void* d_ws, size_t ws_size,
                              hipStream_t stream){
  (void)in_sizes; (void)n_in; (void)out_size; (void)ws_size;
  const float* x      = (const float*)d_in[0];
  const float* mask   = (const float*)d_in[1];
  const float* qkv_w  = (const float*)d_in[2];
  const float* qkv_b  = (const float*)d_in[3];
  const float* rpe    = (const float*)d_in[4];
  const float* proj_w = (const float*)d_in[5];
  const float* proj_b = (const float*)d_in[6];

  ushort* wb   = (ushort*)d_ws;            // 49152
  ushort* pwb  = wb + 49152;               // 16384
  ushort* rpeb = pwb + 16384;              // 240*384 = 92160
  ushort* tvt  = rpeb + 92160;             // 4*32*240 = 30720  (total 376832 B)

  wa_prep<<<360, 256, 0, stream>>>(qkv_w, rpe, proj_w, wb, pwb, rpeb, tvt);
  wa_attn<<<2048, 512, 0, stream>>>(x, mask, qkv_b, proj_b, wb, pwb, rpeb, tvt,
                                    (float*)d_out);
}